// Round 2
// baseline (170.189 us; speedup 1.0000x reference)
//
#include <hip/hip_runtime.h>
#include <math.h>

#define BSZ 512
#define DD 2048
#define KK 128
#define PP 5
#define NCOL (KK * PP)   // 640
#define OUTW (DD + KK)   // 2176

// ws layout (floats): norm[640] | actv[512*640] | f_acc[512*128]
#define WS_NORM 0
#define WS_ACTV (WS_NORM + NCOL)
#define WS_FACC (WS_ACTV + BSZ * NCOL)
#define WS_TOTAL (WS_FACC + BSZ * KK)

// ---------------------------------------------------------------------------
// Kernel 1: column sums of theta^2  ->  norm[col] (atomic accumulate)
// ---------------------------------------------------------------------------
__global__ __launch_bounds__(256) void norm_kernel(const float* __restrict__ theta,
                                                   float* __restrict__ norm) {
    int i   = blockIdx.x * 256 + threadIdx.x;   // 0..40959
    int col = i % NCOL;
    int seg = i / NCOL;                         // 0..63
    const float* p = theta + (size_t)seg * 32 * NCOL + col;
    float s = 0.f;
#pragma unroll
    for (int j = 0; j < 32; ++j) {
        float v = p[(size_t)j * NCOL];
        s += v * v;
    }
    atomicAdd(&norm[col], s);
}

// ---------------------------------------------------------------------------
// Kernel 2: raw GEMM  actv[b, col] = sum_d x[b,d] * theta[d,col]
// fp32 vector ALU. 64x64 tiles, split-K=16 (1280 blocks -> 5 waves/SIMD),
// As padded to stride 68 (2-way banks = free; was 4-way at stride 64).
// ---------------------------------------------------------------------------
#define BM 64
#define BN 64
#define BK 16
#define KSPLIT 16
#define KCHUNK (DD / KSPLIT)   // 128
#define ASTRIDE 68

__global__ __launch_bounds__(256) void gemm_kernel(const float* __restrict__ x,
                                                   const float* __restrict__ theta,
                                                   float* __restrict__ actv) {
    __shared__ float As[BK][ASTRIDE];   // k-major (transposed A tile), padded
    __shared__ float Bs[BK][BN];

    const int t  = threadIdx.x;
    const int tx = t & 15;         // 0..15 -> n micro
    const int ty = t >> 4;         // 0..15 -> m micro
    const int m0 = blockIdx.y * BM;
    const int n0 = blockIdx.x * BN;
    const int kz = blockIdx.z * KCHUNK;

    const int ar = t >> 2;          // 0..63  row of A tile
    const int ac = (t & 3) * 4;     // 0,4,8,12 col group
    const int bk = t >> 4;          // 0..15  row of B tile
    const int bn = (t & 15) * 4;    // col group

    float acc[4][4] = {};

    for (int kb = kz; kb < kz + KCHUNK; kb += BK) {
        const float4 av = *(const float4*)&x[(size_t)(m0 + ar) * DD + kb + ac];
        const float4 bv = *(const float4*)&theta[(size_t)(kb + bk) * NCOL + n0 + bn];
        __syncthreads();
        As[ac + 0][ar] = av.x;
        As[ac + 1][ar] = av.y;
        As[ac + 2][ar] = av.z;
        As[ac + 3][ar] = av.w;
        *(float4*)&Bs[bk][bn] = bv;
        __syncthreads();
#pragma unroll
        for (int kk = 0; kk < BK; ++kk) {
            const float4 a = *(const float4*)&As[kk][ty * 4];
            const float4 b = *(const float4*)&Bs[kk][tx * 4];
            acc[0][0] += a.x * b.x; acc[0][1] += a.x * b.y; acc[0][2] += a.x * b.z; acc[0][3] += a.x * b.w;
            acc[1][0] += a.y * b.x; acc[1][1] += a.y * b.y; acc[1][2] += a.y * b.z; acc[1][3] += a.y * b.w;
            acc[2][0] += a.z * b.x; acc[2][1] += a.z * b.y; acc[2][2] += a.z * b.z; acc[2][3] += a.z * b.w;
            acc[3][0] += a.w * b.x; acc[3][1] += a.w * b.y; acc[3][2] += a.w * b.z; acc[3][3] += a.w * b.w;
        }
    }

#pragma unroll
    for (int i = 0; i < 4; ++i)
#pragma unroll
        for (int j = 0; j < 4; ++j)
            atomicAdd(&actv[(size_t)(m0 + ty * 4 + i) * NCOL + n0 + tx * 4 + j], acc[i][j]);
}

// ---------------------------------------------------------------------------
// Kernel 3: copy x into out[:, 0:D]  (float4)
// ---------------------------------------------------------------------------
__global__ __launch_bounds__(256) void copy_kernel(const float* __restrict__ x,
                                                   float* __restrict__ out) {
    int i = blockIdx.x * 256 + threadIdx.x;
    int r = i >> 9;
    int c = i & 511;
    float4 v = *(const float4*)&x[(size_t)r * DD + c * 4];
    *(float4*)&out[(size_t)r * OUTW + c * 4] = v;
}

// ---------------------------------------------------------------------------
// Kernel 4: per-k pairwise L1 -> exp -> partial rowsum over a 128-wide b2
// chunk. grid (k=128, bhalf=2, q=4) = 1024 blocks -> 4 waves/SIMD.
// Partial sums atomicAdd into f_acc[b][k] (zeroed).
// ---------------------------------------------------------------------------
__global__ __launch_bounds__(256) void pairwise_kernel(const float* __restrict__ actv,
                                                       const float* __restrict__ norm,
                                                       const float* __restrict__ lws,
                                                       float* __restrict__ f_acc) {
    const int k   = blockIdx.x;    // 0..127
    const int q   = blockIdx.z;    // 0..3  (b2 chunk)
    const int tid = threadIdx.x;

    __shared__ float sB[128][8];   // 4 KiB; rows 32B-aligned
    __shared__ float sScale[PP];

    if (tid < PP) {
        const int col = k * PP + tid;
        const float e = __builtin_amdgcn_exp2f(lws[col] * 1.4426950408889634f);
        sScale[tid] = e * __builtin_amdgcn_rsqf(norm[col]);
    }
    __syncthreads();

    // stage this block's 128 b2 rows, scaled
    for (int i = tid; i < 128 * PP; i += 256) {
        int r = i / PP;
        int p = i - r * PP;
        sB[r][p] = actv[(size_t)(q * 128 + r) * NCOL + k * PP + p] * sScale[p];
    }
    __syncthreads();

    const int b = blockIdx.y * 256 + tid;
    const float* arow = &actv[(size_t)b * NCOL + k * PP];
    const float a0 = arow[0] * sScale[0];
    const float a1 = arow[1] * sScale[1];
    const float a2 = arow[2] * sScale[2];
    const float a3 = arow[3] * sScale[3];
    const float a4 = arow[4] * sScale[4];

    const float c = -1.4426950408889634f;
    float acc0 = 0.f, acc1 = 0.f;
#pragma unroll 8
    for (int j = 0; j < 128; j += 2) {
        const float4 v0  = *(const float4*)&sB[j][0];
        const float  v04 = sB[j][4];
        const float4 v1  = *(const float4*)&sB[j + 1][0];
        const float  v14 = sB[j + 1][4];
        float s0 = fabsf(a0 - v0.x) + fabsf(a1 - v0.y) + fabsf(a2 - v0.z) +
                   fabsf(a3 - v0.w) + fabsf(a4 - v04);
        float s1 = fabsf(a0 - v1.x) + fabsf(a1 - v1.y) + fabsf(a2 - v1.z) +
                   fabsf(a3 - v1.w) + fabsf(a4 - v14);
        acc0 += __builtin_amdgcn_exp2f(c * s0);
        acc1 += __builtin_amdgcn_exp2f(c * s1);
    }

    atomicAdd(&f_acc[(size_t)b * KK + k], acc0 + acc1);
}

// ---------------------------------------------------------------------------
// Kernel 5: finalize f -> out[:, D:]   (diag term exp(0)=1 subtracted)
// ---------------------------------------------------------------------------
__global__ __launch_bounds__(256) void finalize_kernel(const float* __restrict__ f_acc,
                                                       const float* __restrict__ bias,
                                                       float* __restrict__ out) {
    int i = blockIdx.x * 256 + threadIdx.x;   // 0..65535
    int b = i >> 7;
    int k = i & 127;
    out[(size_t)b * OUTW + DD + k] = f_acc[i] - 1.0f + bias[k];
}

// ---------------------------------------------------------------------------
extern "C" void kernel_launch(void* const* d_in, const int* in_sizes, int n_in,
                              void* d_out, int out_size, void* d_ws, size_t ws_size,
                              hipStream_t stream) {
    const float* x     = (const float*)d_in[0];   // [512, 2048]
    const float* theta = (const float*)d_in[1];   // [2048, 128, 5]
    const float* lws   = (const float*)d_in[2];   // [128, 5]
    const float* bias  = (const float*)d_in[3];   // [128]
    float* out = (float*)d_out;                   // [512, 2176]

    float* ws    = (float*)d_ws;
    float* norm  = ws + WS_NORM;
    float* actv  = ws + WS_ACTV;
    float* f_acc = ws + WS_FACC;

    hipMemsetAsync(d_ws, 0, (size_t)WS_TOTAL * sizeof(float), stream);

    norm_kernel<<<160, 256, 0, stream>>>(theta, norm);
    gemm_kernel<<<dim3(NCOL / BN, BSZ / BM, KSPLIT), 256, 0, stream>>>(x, theta, actv);
    copy_kernel<<<(BSZ * DD / 4) / 256, 256, 0, stream>>>(x, out);
    pairwise_kernel<<<dim3(KK, 2, 4), 256, 0, stream>>>(actv, norm, lws, f_acc);
    finalize_kernel<<<(BSZ * KK) / 256, 256, 0, stream>>>(f_acc, bias, out);
}

// Round 4
// 126.507 us; speedup vs baseline: 1.3453x; 1.3453x over previous
//
#include <hip/hip_runtime.h>
#include <math.h>

#define BSZ 512
#define DD 2048
#define KK 128
#define PP 5
#define NCOL (KK * PP)   // 640
#define OUTW (DD + KK)   // 2176
#define LOG2E 1.4426950408889634f

#define KSPLIT 8
#define GM 64            // m rows per block (lane dim)
#define GN 64            // n cols per block (4 waves x 16)
#define GK (DD / KSPLIT) // 256 k-depth per split
#define GBK 32           // k chunk staged in LDS

// ws layout (floats):
//   norm[640] | actv[512*640] | f_part[8*128*512] | part[8*512*640]
#define WS_NORM 0
#define WS_ACTV (WS_NORM + NCOL)                    // 640
#define WS_FPART (WS_ACTV + BSZ * NCOL)             // 328320
#define WS_PART (WS_FPART + KSPLIT * KK * BSZ)      // 852608
// total = 3,474,048 floats = 13.9 MB

// ---------------------------------------------------------------------------
// Kernel 1: column sums of theta^2 -> norm[col] (atomic, tiny: 640 floats)
// ---------------------------------------------------------------------------
__global__ __launch_bounds__(256) void norm_kernel(const float* __restrict__ theta,
                                                   float* __restrict__ norm) {
    int i   = blockIdx.x * 256 + threadIdx.x;   // 0..40959
    int col = i % NCOL;
    int seg = i / NCOL;                         // 0..63
    const float* p = theta + (size_t)seg * 32 * NCOL + col;
    float s = 0.f;
#pragma unroll
    for (int j = 0; j < 32; ++j) {
        float v = p[(size_t)j * NCOL];
        s += v * v;
    }
    atomicAdd(&norm[col], s);
}

// ---------------------------------------------------------------------------
// Kernel 2: split-K GEMM, scalar-B form.
// Wave: lane = m row (64 rows), 16 n-cols per wave (acc[16]).
// A (x) staged in LDS [kk][64], read ds_read_b32 conflict-free.
// B (theta) read via wave-uniform (SGPR) addresses -> s_load, scalar pipe.
// Partials -> part[z][m][n], plain float4 stores (NO atomics).
// ---------------------------------------------------------------------------
__global__ __launch_bounds__(256) void gemm_kernel(const float* __restrict__ x,
                                                   const float* __restrict__ theta,
                                                   float* __restrict__ part) {
    __shared__ float xT[GBK][GM];   // [kk][m], 8 KiB

    const int t    = threadIdx.x;
    const int lane = t & 63;
    const int wave = t >> 6;                 // 0..3
    const int m    = blockIdx.y * GM + lane;
    const int kz   = blockIdx.z * GK;
    // wave-uniform n base -> forces SGPR addressing for theta
    const int nw = __builtin_amdgcn_readfirstlane(blockIdx.x * GN + wave * 16);

    float acc[16] = {};

    for (int kc = kz; kc < kz + GK; kc += GBK) {
        // stage: wave w fills kk rows [w*8, w*8+8), lane = m  (conflict-free)
        const float4 v0 = *(const float4*)&x[(size_t)m * DD + kc + wave * 8];
        const float4 v1 = *(const float4*)&x[(size_t)m * DD + kc + wave * 8 + 4];
        __syncthreads();   // previous chunk's reads complete
        xT[wave * 8 + 0][lane] = v0.x;
        xT[wave * 8 + 1][lane] = v0.y;
        xT[wave * 8 + 2][lane] = v0.z;
        xT[wave * 8 + 3][lane] = v0.w;
        xT[wave * 8 + 4][lane] = v1.x;
        xT[wave * 8 + 5][lane] = v1.y;
        xT[wave * 8 + 6][lane] = v1.z;
        xT[wave * 8 + 7][lane] = v1.w;
        __syncthreads();

        const float* th = &theta[(size_t)kc * NCOL + nw];
#pragma unroll 4
        for (int kk = 0; kk < GBK; ++kk) {
            const float a = xT[kk][lane];
#pragma unroll
            for (int j = 0; j < 16; ++j)
                acc[j] += a * th[(size_t)kk * NCOL + j];   // th[..] wave-uniform -> s_load
        }
    }

    float* dst = part + (size_t)blockIdx.z * (BSZ * NCOL) + (size_t)m * NCOL + nw;
    *(float4*)&dst[0]  = make_float4(acc[0],  acc[1],  acc[2],  acc[3]);
    *(float4*)&dst[4]  = make_float4(acc[4],  acc[5],  acc[6],  acc[7]);
    *(float4*)&dst[8]  = make_float4(acc[8],  acc[9],  acc[10], acc[11]);
    *(float4*)&dst[12] = make_float4(acc[12], acc[13], acc[14], acc[15]);
}

// ---------------------------------------------------------------------------
// Kernel 3: reduce split-K partials, fold in scale = exp(lws)/norm * log2e.
// actv is therefore pre-scaled by log2(e): pairwise uses exp2 directly.
// ---------------------------------------------------------------------------
__global__ __launch_bounds__(256) void reduce_kernel(const float* __restrict__ part,
                                                     const float* __restrict__ norm,
                                                     const float* __restrict__ lws,
                                                     float* __restrict__ actv) {
    int i   = blockIdx.x * 256 + threadIdx.x;   // 0..327679
    int col = i % NCOL;
    float s = 0.f;
#pragma unroll
    for (int q = 0; q < KSPLIT; ++q)
        s += part[(size_t)q * (BSZ * NCOL) + i];
    const float scale = __builtin_amdgcn_exp2f(lws[col] * LOG2E) *
                        __builtin_amdgcn_rsqf(norm[col]) * LOG2E;
    actv[i] = s * scale;
}

// ---------------------------------------------------------------------------
// Kernel 4: copy x into out[:, 0:D]  (float4)
// ---------------------------------------------------------------------------
__global__ __launch_bounds__(256) void copy_kernel(const float* __restrict__ x,
                                                   float* __restrict__ out) {
    int i = blockIdx.x * 256 + threadIdx.x;
    int r = i >> 9;
    int c = i & 511;
    float4 v = *(const float4*)&x[(size_t)r * DD + c * 4];
    *(float4*)&out[(size_t)r * OUTW + c * 4] = v;
}

// ---------------------------------------------------------------------------
// Kernel 5: pairwise L1 -> exp2 -> partial rowsum over 64-wide b2 chunk.
// grid (k=128, q=8) = 1024 blocks x 4 waves = 4 waves/SIMD.
// Each thread owns 2 b rows (tid, tid+256): halves LDS reads per pair.
// Plain stores to f_part[q][k][b] (coalesced per block). No atomics.
// FIX vs R2: staging needs 320 entries but block is 256 threads -> strided
// loop (rows 51..63 previously held 0xAA poison => absmax 7.125).
// ---------------------------------------------------------------------------
__global__ __launch_bounds__(256) void pairwise_kernel(const float* __restrict__ actv,
                                                       float* __restrict__ f_part) {
    const int k   = blockIdx.x;    // 0..127
    const int q   = blockIdx.y;    // 0..7
    const int tid = threadIdx.x;

    __shared__ float sB[64][8];    // 2 KiB, rows 32B-aligned

    for (int i = tid; i < 64 * PP; i += 256) {   // 320 entries, 2 iterations
        int r = i / PP;
        int p = i - r * PP;
        sB[r][p] = actv[(size_t)(q * 64 + r) * NCOL + k * PP + p];
    }

    const float* a0p = &actv[(size_t)tid * NCOL + k * PP];
    const float* a1p = &actv[(size_t)(tid + 256) * NCOL + k * PP];
    const float a00 = a0p[0], a01 = a0p[1], a02 = a0p[2], a03 = a0p[3], a04 = a0p[4];
    const float a10 = a1p[0], a11 = a1p[1], a12 = a1p[2], a13 = a1p[3], a14 = a1p[4];
    __syncthreads();

    float acc0 = 0.f, acc1 = 0.f;
#pragma unroll 4
    for (int j = 0; j < 64; ++j) {
        const float4 v  = *(const float4*)&sB[j][0];
        const float  v4 = sB[j][4];
        float s0 = fabsf(a00 - v.x) + fabsf(a01 - v.y) + fabsf(a02 - v.z) +
                   fabsf(a03 - v.w) + fabsf(a04 - v4);
        float s1 = fabsf(a10 - v.x) + fabsf(a11 - v.y) + fabsf(a12 - v.z) +
                   fabsf(a13 - v.w) + fabsf(a14 - v4);
        acc0 += __builtin_amdgcn_exp2f(-s0);   // actv pre-scaled by log2e
        acc1 += __builtin_amdgcn_exp2f(-s1);
    }

    float* fp = f_part + ((size_t)q * KK + k) * BSZ;
    fp[tid]       = acc0;
    fp[tid + 256] = acc1;
}

// ---------------------------------------------------------------------------
// Kernel 6: finalize f -> out[:, D:]   (diag term exp(0)=1 subtracted)
// ---------------------------------------------------------------------------
__global__ __launch_bounds__(256) void finalize_kernel(const float* __restrict__ f_part,
                                                       const float* __restrict__ bias,
                                                       float* __restrict__ out) {
    int i = blockIdx.x * 256 + threadIdx.x;   // 0..65535
    int k = i >> 9;          // 0..127
    int b = i & 511;         // lanes vary b -> coalesced reads
    float s = 0.f;
#pragma unroll
    for (int q = 0; q < KSPLIT; ++q)
        s += f_part[((size_t)q * KK + k) * BSZ + b];
    out[(size_t)b * OUTW + DD + k] = s - 1.0f + bias[k];
}

// ---------------------------------------------------------------------------
extern "C" void kernel_launch(void* const* d_in, const int* in_sizes, int n_in,
                              void* d_out, int out_size, void* d_ws, size_t ws_size,
                              hipStream_t stream) {
    const float* x     = (const float*)d_in[0];   // [512, 2048]
    const float* theta = (const float*)d_in[1];   // [2048, 128, 5]
    const float* lws   = (const float*)d_in[2];   // [128, 5]
    const float* bias  = (const float*)d_in[3];   // [128]
    float* out = (float*)d_out;                   // [512, 2176]

    float* ws     = (float*)d_ws;
    float* norm   = ws + WS_NORM;
    float* actv   = ws + WS_ACTV;
    float* f_part = ws + WS_FPART;
    float* part   = ws + WS_PART;

    // only the tiny atomic target needs zeroing
    hipMemsetAsync(norm, 0, NCOL * sizeof(float), stream);

    norm_kernel<<<160, 256, 0, stream>>>(theta, norm);
    gemm_kernel<<<dim3(NCOL / GN, BSZ / GM, KSPLIT), 256, 0, stream>>>(x, theta, part);
    reduce_kernel<<<(BSZ * NCOL) / 256, 256, 0, stream>>>(part, norm, lws, actv);
    copy_kernel<<<(BSZ * DD / 4) / 256, 256, 0, stream>>>(x, out);
    pairwise_kernel<<<dim3(KK, KSPLIT), 256, 0, stream>>>(actv, f_part);
    finalize_kernel<<<(BSZ * KK) / 256, 256, 0, stream>>>(f_part, bias, out);
}

// Round 5
// 121.931 us; speedup vs baseline: 1.3958x; 1.0375x over previous
//
#include <hip/hip_runtime.h>
#include <math.h>

#define BSZ 512
#define DD 2048
#define KK 128
#define PP 5
#define NCOL (KK * PP)   // 640
#define OUTW (DD + KK)   // 2176
#define LOG2E 1.4426950408889634f

#define KSPLIT 16
#define GM 64            // m rows per block (lane dim)
#define GN 64            // n cols per block (4 waves x 16)
#define GK (DD / KSPLIT) // 128 k-depth per split
#define GBK 32           // k chunk staged in LDS
#define QSPLIT 8         // pairwise b2 chunks

// ws layout (floats):
#define WS_NORM 0
#define WS_ACTV (WS_NORM + NCOL)                      // 640
#define WS_FPART (WS_ACTV + BSZ * NCOL)               // 328320
#define WS_PART (WS_FPART + QSPLIT * KK * BSZ)        // 852608
// part = 16*512*640 = 5,242,880 floats; total ~24.4 MB

// ---------------------------------------------------------------------------
// Kernel 1: column sums of theta^2 -> norm[col]. 320 blocks, 16 rows/thread.
// ---------------------------------------------------------------------------
__global__ __launch_bounds__(256) void norm_kernel(const float* __restrict__ theta,
                                                   float* __restrict__ norm) {
    int i   = blockIdx.x * 256 + threadIdx.x;   // 0..81919
    int col = i % NCOL;
    int seg = i / NCOL;                         // 0..127
    const float* p = theta + (size_t)seg * 16 * NCOL + col;
    float s = 0.f;
#pragma unroll
    for (int j = 0; j < 16; ++j) {
        float v = p[(size_t)j * NCOL];
        s += v * v;
    }
    atomicAdd(&norm[col], s);
}

// ---------------------------------------------------------------------------
// Kernel 2: split-K GEMM, scalar-B form, software-pipelined staging.
// Wave: lane = m row, 16 n-cols per wave. A (x) in LDS (ds_read_b32,
// 2-way=free). B (theta) via wave-uniform SGPR addresses -> s_load.
// KSPLIT=16 -> 1280 blocks -> 5 waves/SIMD. Plain float4 stores, no atomics.
// ---------------------------------------------------------------------------
__global__ __launch_bounds__(256) void gemm_kernel(const float* __restrict__ x,
                                                   const float* __restrict__ theta,
                                                   float* __restrict__ part) {
    __shared__ float xT[GBK][GM];   // [kk][m], 8 KiB

    const int t    = threadIdx.x;
    const int lane = t & 63;
    const int wave = t >> 6;                 // 0..3
    const int m    = blockIdx.y * GM + lane;
    const int kz   = blockIdx.z * GK;
    const int nw = __builtin_amdgcn_readfirstlane(blockIdx.x * GN + wave * 16);

    const float* xrow = x + (size_t)m * DD;

    float acc[16] = {};

    // prefetch first chunk
    float4 v0 = *(const float4*)&xrow[kz + wave * 8];
    float4 v1 = *(const float4*)&xrow[kz + wave * 8 + 4];

    for (int kc = kz; kc < kz + GK; kc += GBK) {
        __syncthreads();   // previous chunk's LDS reads complete
        xT[wave * 8 + 0][lane] = v0.x;
        xT[wave * 8 + 1][lane] = v0.y;
        xT[wave * 8 + 2][lane] = v0.z;
        xT[wave * 8 + 3][lane] = v0.w;
        xT[wave * 8 + 4][lane] = v1.x;
        xT[wave * 8 + 5][lane] = v1.y;
        xT[wave * 8 + 6][lane] = v1.z;
        xT[wave * 8 + 7][lane] = v1.w;
        __syncthreads();

        // issue next chunk's global loads now; in flight during compute
        if (kc + GBK < kz + GK) {
            v0 = *(const float4*)&xrow[kc + GBK + wave * 8];
            v1 = *(const float4*)&xrow[kc + GBK + wave * 8 + 4];
        }

        const float* th = &theta[(size_t)kc * NCOL + nw];
#pragma unroll 4
        for (int kk = 0; kk < GBK; ++kk) {
            const float a = xT[kk][lane];
#pragma unroll
            for (int j = 0; j < 16; ++j)
                acc[j] += a * th[(size_t)kk * NCOL + j];   // wave-uniform -> s_load
        }
    }

    float* dst = part + (size_t)blockIdx.z * (BSZ * NCOL) + (size_t)m * NCOL + nw;
    *(float4*)&dst[0]  = make_float4(acc[0],  acc[1],  acc[2],  acc[3]);
    *(float4*)&dst[4]  = make_float4(acc[4],  acc[5],  acc[6],  acc[7]);
    *(float4*)&dst[8]  = make_float4(acc[8],  acc[9],  acc[10], acc[11]);
    *(float4*)&dst[12] = make_float4(acc[12], acc[13], acc[14], acc[15]);
}

// ---------------------------------------------------------------------------
// Kernel 3: reduce 16 split-K partials, fold scale = exp(lws)/norm * log2e.
// ---------------------------------------------------------------------------
__global__ __launch_bounds__(256) void reduce_kernel(const float* __restrict__ part,
                                                     const float* __restrict__ norm,
                                                     const float* __restrict__ lws,
                                                     float* __restrict__ actv) {
    int i   = blockIdx.x * 256 + threadIdx.x;   // 0..327679
    int col = i % NCOL;
    float s = 0.f;
#pragma unroll
    for (int q = 0; q < KSPLIT; ++q)
        s += part[(size_t)q * (BSZ * NCOL) + i];
    const float scale = __builtin_amdgcn_exp2f(lws[col] * LOG2E) *
                        __builtin_amdgcn_rsqf(norm[col]) * LOG2E;
    actv[i] = s * scale;
}

// ---------------------------------------------------------------------------
// Kernel 4: pairwise L1 -> exp2 -> partial rowsum over 64-wide b2 chunk.
// Block = 128 threads, 4 b-rows each (tid+{0,128,256,384}): per b2 iteration
// 2 DS insts feed 4 rows of VALU -> VALU-bound (was DS-bound at 2 rows).
// grid (k=128, q=8) = 1024 blocks x 2 waves.
// ---------------------------------------------------------------------------
__global__ __launch_bounds__(128) void pairwise_kernel(const float* __restrict__ actv,
                                                       float* __restrict__ f_part) {
    const int k   = blockIdx.x;    // 0..127
    const int q   = blockIdx.y;    // 0..7
    const int tid = threadIdx.x;   // 0..127

    __shared__ float sB[64][8];    // 2 KiB, rows 32B-aligned

    for (int i = tid; i < 64 * PP; i += 128) {   // 320 entries, 3 iterations
        int r = i / PP;
        int p = i - r * PP;
        sB[r][p] = actv[(size_t)(q * 64 + r) * NCOL + k * PP + p];
    }

    float a[4][PP];
#pragma unroll
    for (int r = 0; r < 4; ++r) {
        const float* ap = &actv[(size_t)(tid + r * 128) * NCOL + k * PP];
#pragma unroll
        for (int p = 0; p < PP; ++p) a[r][p] = ap[p];
    }
    __syncthreads();

    float acc[4] = {0.f, 0.f, 0.f, 0.f};
#pragma unroll 2
    for (int j = 0; j < 64; ++j) {
        const float4 v  = *(const float4*)&sB[j][0];
        const float  v4 = sB[j][4];
#pragma unroll
        for (int r = 0; r < 4; ++r) {
            float s = fabsf(a[r][0] - v.x) + fabsf(a[r][1] - v.y) +
                      fabsf(a[r][2] - v.z) + fabsf(a[r][3] - v.w) +
                      fabsf(a[r][4] - v4);
            acc[r] += __builtin_amdgcn_exp2f(-s);   // actv pre-scaled by log2e
        }
    }

    float* fp = f_part + ((size_t)q * KK + k) * BSZ;
#pragma unroll
    for (int r = 0; r < 4; ++r)
        fp[tid + r * 128] = acc[r];
}

// ---------------------------------------------------------------------------
// Kernel 5: epilogue — blocks [0,1024) copy x -> out[:, :D] (float4);
// blocks [1024,1280) reduce f_part -> out[:, D:]. Block-uniform branch.
// ---------------------------------------------------------------------------
__global__ __launch_bounds__(256) void epilogue_kernel(const float* __restrict__ x,
                                                       const float* __restrict__ f_part,
                                                       const float* __restrict__ bias,
                                                       float* __restrict__ out) {
    const int bid = blockIdx.x;
    if (bid < 1024) {
        int i = bid * 256 + threadIdx.x;   // 0..262143 (512 rows * 512 f4)
        int r = i >> 9;
        int c = i & 511;
        float4 v = *(const float4*)&x[(size_t)r * DD + c * 4];
        *(float4*)&out[(size_t)r * OUTW + c * 4] = v;
    } else {
        int i = (bid - 1024) * 256 + threadIdx.x;   // 0..65535
        int k = i >> 9;          // 0..127
        int b = i & 511;
        float s = 0.f;
#pragma unroll
        for (int q = 0; q < QSPLIT; ++q)
            s += f_part[((size_t)q * KK + k) * BSZ + b];
        out[(size_t)b * OUTW + DD + k] = s - 1.0f + bias[k];
    }
}

// ---------------------------------------------------------------------------
extern "C" void kernel_launch(void* const* d_in, const int* in_sizes, int n_in,
                              void* d_out, int out_size, void* d_ws, size_t ws_size,
                              hipStream_t stream) {
    const float* x     = (const float*)d_in[0];   // [512, 2048]
    const float* theta = (const float*)d_in[1];   // [2048, 128, 5]
    const float* lws   = (const float*)d_in[2];   // [128, 5]
    const float* bias  = (const float*)d_in[3];   // [128]
    float* out = (float*)d_out;                   // [512, 2176]

    float* ws     = (float*)d_ws;
    float* norm   = ws + WS_NORM;
    float* actv   = ws + WS_ACTV;
    float* f_part = ws + WS_FPART;
    float* part   = ws + WS_PART;

    hipMemsetAsync(norm, 0, NCOL * sizeof(float), stream);

    norm_kernel<<<320, 256, 0, stream>>>(theta, norm);
    gemm_kernel<<<dim3(NCOL / GN, BSZ / GM, KSPLIT), 256, 0, stream>>>(x, theta, part);
    reduce_kernel<<<(BSZ * NCOL) / 256, 256, 0, stream>>>(part, norm, lws, actv);
    pairwise_kernel<<<dim3(KK, QSPLIT), 128, 0, stream>>>(actv, f_part);
    epilogue_kernel<<<1280, 256, 0, stream>>>(x, f_part, bias, out);
}